// Round 1
// baseline (2139.045 us; speedup 1.0000x reference)
//
#include <hip/hip_runtime.h>
#include <hip/hip_bf16.h>

#define EPS_BN 1e-5f

// ---------------------------------------------------------------- utilities
__global__ void zero_i32(int* __restrict__ p, int n) {
    int i = blockIdx.x * blockDim.x + threadIdx.x;
    if (i < n) p[i] = 0;
}
__global__ void zero_f32(float* __restrict__ p, int n) {
    int i = blockIdx.x * blockDim.x + threadIdx.x;
    if (i < n) p[i] = 0.0f;
}

// out[C][R] = in[R][C]^T   (weights are tiny; coalescing irrelevant)
__global__ void transpose_k(const float* __restrict__ in, float* __restrict__ out, int R, int C) {
    int i = blockIdx.x * blockDim.x + threadIdx.x;
    if (i < R * C) {
        int r = i / C, c = i % C;
        out[c * R + r] = in[i];
    }
}

// ---------------------------------------------------------------- CSR build
__global__ void count_k(const int* __restrict__ dst, int* __restrict__ counts, int E) {
    int i = blockIdx.x * blockDim.x + threadIdx.x;
    if (i < E) atomicAdd(&counts[dst[i]], 1);
}

// per-block exclusive scan (256 elems) + block totals
__global__ void scan1(const int* __restrict__ counts, int* __restrict__ rp,
                      int* __restrict__ partials, int n) {
    __shared__ int s[256];
    int t = threadIdx.x;
    int i = blockIdx.x * 256 + t;
    int v = (i < n) ? counts[i] : 0;
    s[t] = v;
    __syncthreads();
    for (int off = 1; off < 256; off <<= 1) {
        int u = (t >= off) ? s[t - off] : 0;
        __syncthreads();
        s[t] += u;
        __syncthreads();
    }
    if (i < n) rp[i] = s[t] - v;           // exclusive, local to block
    if (t == 255) partials[blockIdx.x] = s[255];
}

// single-block scan of block totals (nb <= 512)
__global__ void scan2(int* __restrict__ partials, int nb) {
    __shared__ int s[512];
    int t = threadIdx.x;
    int v = (t < nb) ? partials[t] : 0;
    s[t] = v;
    __syncthreads();
    for (int off = 1; off < 512; off <<= 1) {
        int u = (t >= off) ? s[t - off] : 0;
        __syncthreads();
        s[t] += u;
        __syncthreads();
    }
    if (t < nb) partials[t] = s[t] - v;    // exclusive
}

__global__ void scan3(int* __restrict__ rp, const int* __restrict__ partials, int n, int E) {
    int i = blockIdx.x * blockDim.x + threadIdx.x;
    if (i < n) rp[i] += partials[i >> 8];
    if (i == 0) rp[n] = E;
}

__global__ void fill_k(const int* __restrict__ src, const int* __restrict__ dst,
                       const int* __restrict__ rp, int* __restrict__ cursor,
                       int* __restrict__ col, int E) {
    int i = blockIdx.x * blockDim.x + threadIdx.x;
    if (i < E) {
        int d = dst[i];
        int pos = atomicAdd(&cursor[d], 1);
        col[rp[d] + pos] = src[i];
    }
}

// ------------------------------------------------------- gather aggregation
// one block per dst node; thread = feature. mean of neighbor rows.
__global__ void aggregate_k(const float* __restrict__ x, const int* __restrict__ rp,
                            const int* __restrict__ col, float* __restrict__ agg, int d) {
    int n = blockIdx.x;
    int f = threadIdx.x;
    int s = rp[n], e = rp[n + 1];
    float scale = 1.0f / fmaxf((float)(e - s), 1.0f);
    if (f < d) {
        float acc = 0.0f;
        for (int i = s; i < e; ++i) {
            int srcn = col[i];
            acc += x[(size_t)srcn * d + f];
        }
        agg[(size_t)n * d + f] = acc * scale;
    }
}

// ------------------------------------------------- fused SAGE linear (fp32)
// out[n][f] = bias[f] + sum_k Wrt[k][f]*x[n][k] (+ Wlt[k][f]*agg[n][k]); opt relu
// Block: 32 nodes x D_OUT features, 256 threads.
template <int D_IN, int D_OUT, bool RELU, bool HAS_AGG>
__global__ __launch_bounds__(256) void sage_linear(
    const float* __restrict__ x, const float* __restrict__ agg,
    const float* __restrict__ Wrt, const float* __restrict__ Wlt,
    const float* __restrict__ bias, float* __restrict__ out) {
    constexpr int NT = 32;
    constexpr int FG = D_OUT / 4;   // feature groups of 4
    constexpr int NG = 256 / FG;    // node subgroups
    constexpr int NPT = NT / NG;    // nodes per thread
    __shared__ __align__(16) float xs[NT * D_IN];
    __shared__ __align__(16) float as_[HAS_AGG ? NT * D_IN : 4];

    const int t = threadIdx.x;
    const size_t base = (size_t)blockIdx.x * NT;

    // stage tiles (rows are contiguous -> flat float4 copy)
    constexpr int NV = NT * D_IN / 4;
    const float4* x4 = (const float4*)(x + base * D_IN);
    float4* xs4 = (float4*)xs;
    for (int i = t; i < NV; i += 256) xs4[i] = x4[i];
    if constexpr (HAS_AGG) {
        const float4* a4 = (const float4*)(agg + base * D_IN);
        float4* as4 = (float4*)as_;
        for (int i = t; i < NV; i += 256) as4[i] = a4[i];
    }
    __syncthreads();

    const int tf = t % FG;
    const int tn = t / FG;
    const int f0 = tf * 4;

    float4 b4 = *(const float4*)(bias + f0);
    float acc[NPT][4];
#pragma unroll
    for (int i = 0; i < NPT; ++i) {
        acc[i][0] = b4.x; acc[i][1] = b4.y; acc[i][2] = b4.z; acc[i][3] = b4.w;
    }

    for (int k = 0; k < D_IN; k += 4) {
        float4 wr0 = *(const float4*)(Wrt + (size_t)(k + 0) * D_OUT + f0);
        float4 wr1 = *(const float4*)(Wrt + (size_t)(k + 1) * D_OUT + f0);
        float4 wr2 = *(const float4*)(Wrt + (size_t)(k + 2) * D_OUT + f0);
        float4 wr3 = *(const float4*)(Wrt + (size_t)(k + 3) * D_OUT + f0);
        float4 wl0, wl1, wl2, wl3;
        if constexpr (HAS_AGG) {
            wl0 = *(const float4*)(Wlt + (size_t)(k + 0) * D_OUT + f0);
            wl1 = *(const float4*)(Wlt + (size_t)(k + 1) * D_OUT + f0);
            wl2 = *(const float4*)(Wlt + (size_t)(k + 2) * D_OUT + f0);
            wl3 = *(const float4*)(Wlt + (size_t)(k + 3) * D_OUT + f0);
        }
#pragma unroll
        for (int i = 0; i < NPT; ++i) {
            int nn = tn * NPT + i;
            float4 xv = *(const float4*)(xs + nn * D_IN + k);
            acc[i][0] += wr0.x * xv.x + wr1.x * xv.y + wr2.x * xv.z + wr3.x * xv.w;
            acc[i][1] += wr0.y * xv.x + wr1.y * xv.y + wr2.y * xv.z + wr3.y * xv.w;
            acc[i][2] += wr0.z * xv.x + wr1.z * xv.y + wr2.z * xv.z + wr3.z * xv.w;
            acc[i][3] += wr0.w * xv.x + wr1.w * xv.y + wr2.w * xv.z + wr3.w * xv.w;
            if constexpr (HAS_AGG) {
                float4 av = *(const float4*)(as_ + nn * D_IN + k);
                acc[i][0] += wl0.x * av.x + wl1.x * av.y + wl2.x * av.z + wl3.x * av.w;
                acc[i][1] += wl0.y * av.x + wl1.y * av.y + wl2.y * av.z + wl3.y * av.w;
                acc[i][2] += wl0.z * av.x + wl1.z * av.y + wl2.z * av.z + wl3.z * av.w;
                acc[i][3] += wl0.w * av.x + wl1.w * av.y + wl2.w * av.z + wl3.w * av.w;
            }
        }
    }

#pragma unroll
    for (int i = 0; i < NPT; ++i) {
        int nn = tn * NPT + i;
        float4 v;
        v.x = acc[i][0]; v.y = acc[i][1]; v.z = acc[i][2]; v.w = acc[i][3];
        if (RELU) {
            v.x = fmaxf(v.x, 0.0f); v.y = fmaxf(v.y, 0.0f);
            v.z = fmaxf(v.z, 0.0f); v.w = fmaxf(v.w, 0.0f);
        }
        *(float4*)(out + (base + nn) * D_OUT + f0) = v;
    }
}

// ---------------------------------------------------------------- BatchNorm
__global__ void bn_partial(const float* __restrict__ z, float* __restrict__ sums, int n) {
    int f = threadIdx.x & 127;
    int half = threadIdx.x >> 7;
    float s = 0.0f, s2 = 0.0f;
    for (int row = blockIdx.x * 2 + half; row < n; row += gridDim.x * 2) {
        float v = z[(size_t)row * 128 + f];
        s += v; s2 += v * v;
    }
    __shared__ float ls[256], ls2[256];
    ls[threadIdx.x] = s; ls2[threadIdx.x] = s2;
    __syncthreads();
    if (half == 0) {
        atomicAdd(&sums[f], s + ls[128 + f]);
        atomicAdd(&sums[128 + f], s2 + ls2[128 + f]);
    }
}

__global__ void bn_finalize(const float* __restrict__ sums, const float* __restrict__ gamma,
                            const float* __restrict__ beta, float* __restrict__ params, int n) {
    int f = threadIdx.x;  // 128 threads
    float mu = sums[f] / (float)n;
    float var = sums[128 + f] / (float)n - mu * mu;
    float inv = rsqrtf(var + EPS_BN);
    float sc = gamma[f] * inv;
    params[f] = sc;
    params[128 + f] = beta[f] - mu * sc;
}

__global__ void bn_apply(float* __restrict__ z, const float* __restrict__ params, int total4) {
    int i = blockIdx.x * blockDim.x + threadIdx.x;
    for (; i < total4; i += gridDim.x * blockDim.x) {
        float4 v = ((float4*)z)[i];
        int f0 = (i & 31) * 4;
        v.x = v.x * params[f0 + 0] + params[128 + f0 + 0];
        v.y = v.y * params[f0 + 1] + params[128 + f0 + 1];
        v.z = v.z * params[f0 + 2] + params[128 + f0 + 2];
        v.w = v.w * params[f0 + 3] + params[128 + f0 + 3];
        ((float4*)z)[i] = v;
    }
}

// ---------------------------------------------------------------- launcher
extern "C" void kernel_launch(void* const* d_in, const int* in_sizes, int n_in,
                              void* d_out, int out_size, void* d_ws, size_t ws_size,
                              hipStream_t stream) {
    const float* x_in  = (const float*)d_in[0];
    const int*   ei    = (const int*)d_in[1];
    const float* Wl0   = (const float*)d_in[2];
    const float* bl0   = (const float*)d_in[3];
    const float* Wr0   = (const float*)d_in[4];
    const float* Wl1   = (const float*)d_in[5];
    const float* bl1   = (const float*)d_in[6];
    const float* Wr1   = (const float*)d_in[7];
    const float* Wl2   = (const float*)d_in[8];
    const float* bl2   = (const float*)d_in[9];
    const float* Wr2   = (const float*)d_in[10];
    const float* Wp    = (const float*)d_in[11];
    const float* bp    = (const float*)d_in[12];
    const float* gamma = (const float*)d_in[13];
    const float* beta  = (const float*)d_in[14];

    const int IN = 100, H = 256, OUT = 256, P = 128;
    const int n = in_sizes[0] / IN;          // 100000
    const int E = in_sizes[1] / 2;           // 1600000
    const int* src = ei;
    const int* dst = ei + E;

    // workspace carve (256B aligned)
    size_t off = 0;
    auto alloc = [&](size_t bytes) -> char* {
        char* p = (char*)d_ws + off;
        off += (bytes + 255) & ~(size_t)255;
        return p;
    };
    int*   counts   = (int*)alloc((size_t)n * 4);
    int*   cursor   = (int*)alloc((size_t)n * 4);
    int*   rp       = (int*)alloc((size_t)(n + 1) * 4);
    int*   partials = (int*)alloc(512 * 4);
    int*   col      = (int*)alloc((size_t)E * 4);
    float* Wl0t = (float*)alloc((size_t)IN * H * 4);
    float* Wr0t = (float*)alloc((size_t)IN * H * 4);
    float* Wl1t = (float*)alloc((size_t)H * H * 4);
    float* Wr1t = (float*)alloc((size_t)H * H * 4);
    float* Wl2t = (float*)alloc((size_t)H * OUT * 4);
    float* Wr2t = (float*)alloc((size_t)H * OUT * 4);
    float* Wpt  = (float*)alloc((size_t)OUT * P * 4);
    float* bnsums   = (float*)alloc(256 * 4);
    float* bnparams = (float*)alloc(256 * 4);
    float* aggbuf = (float*)alloc((size_t)n * H * 4);   // 102.4 MB
    float* h2     = (float*)alloc((size_t)n * H * 4);   // 102.4 MB

    float* out_x = (float*)d_out;                  // [n,256] final x (also h1 temp)
    float* z     = out_x + (size_t)n * OUT;        // [n,128] projection/BN output
    float* h1    = out_x;                          // layer0 output time-shares x region

    const int nb = (n + 255) / 256;

    // --- CSR build ---
    zero_i32<<<(n + 255) / 256, 256, 0, stream>>>(counts, n);
    zero_i32<<<(n + 255) / 256, 256, 0, stream>>>(cursor, n);
    zero_f32<<<1, 256, 0, stream>>>(bnsums, 256);
    count_k<<<(E + 255) / 256, 256, 0, stream>>>(dst, counts, E);
    scan1<<<nb, 256, 0, stream>>>(counts, rp, partials, n);
    scan2<<<1, 512, 0, stream>>>(partials, nb);
    scan3<<<(n + 255) / 256, 256, 0, stream>>>(rp, partials, n, E);
    fill_k<<<(E + 255) / 256, 256, 0, stream>>>(src, dst, rp, cursor, col, E);

    // --- weight transposes ---
    transpose_k<<<(H * IN + 255) / 256, 256, 0, stream>>>(Wl0, Wl0t, H, IN);
    transpose_k<<<(H * IN + 255) / 256, 256, 0, stream>>>(Wr0, Wr0t, H, IN);
    transpose_k<<<(H * H + 255) / 256, 256, 0, stream>>>(Wl1, Wl1t, H, H);
    transpose_k<<<(H * H + 255) / 256, 256, 0, stream>>>(Wr1, Wr1t, H, H);
    transpose_k<<<(H * H + 255) / 256, 256, 0, stream>>>(Wl2, Wl2t, OUT, H);
    transpose_k<<<(H * H + 255) / 256, 256, 0, stream>>>(Wr2, Wr2t, OUT, H);
    transpose_k<<<(P * H + 255) / 256, 256, 0, stream>>>(Wp, Wpt, P, H);

    // --- layer 0: IN=100 -> H=256, relu ---
    aggregate_k<<<n, 128, 0, stream>>>(x_in, rp, col, aggbuf, IN);
    sage_linear<100, 256, true, true><<<n / 32, 256, 0, stream>>>(
        x_in, aggbuf, Wr0t, Wl0t, bl0, h1);

    // --- layer 1: 256 -> 256, relu ---
    aggregate_k<<<n, 256, 0, stream>>>(h1, rp, col, aggbuf, H);
    sage_linear<256, 256, true, true><<<n / 32, 256, 0, stream>>>(
        h1, aggbuf, Wr1t, Wl1t, bl1, h2);

    // --- layer 2: 256 -> 256, no relu, output -> d_out x region ---
    aggregate_k<<<n, 256, 0, stream>>>(h2, rp, col, aggbuf, H);
    sage_linear<256, 256, false, true><<<n / 32, 256, 0, stream>>>(
        h2, aggbuf, Wr2t, Wl2t, bl2, out_x);

    // --- projection head: 256 -> 128 ---
    sage_linear<256, 128, false, false><<<n / 32, 256, 0, stream>>>(
        out_x, nullptr, Wpt, nullptr, bp, z);

    // --- BatchNorm over z ---
    bn_partial<<<256, 256, 0, stream>>>(z, bnsums, n);
    bn_finalize<<<1, 128, 0, stream>>>(bnsums, gamma, beta, bnparams, n);
    bn_apply<<<2048, 256, 0, stream>>>(z, bnparams, n * (P / 4));
}

// Round 2
// 982.572 us; speedup vs baseline: 2.1770x; 2.1770x over previous
//
#include <hip/hip_runtime.h>
#include <hip/hip_bf16.h>

#define EPS_BN 1e-5f

using short8 = __attribute__((ext_vector_type(8))) short;
using f32x4  = __attribute__((ext_vector_type(4))) float;

__device__ inline float bf2f(unsigned short u) {
    union { unsigned i; float f; } c; c.i = ((unsigned)u) << 16; return c.f;
}
__device__ inline unsigned short f2bf(float f) {
    unsigned x = __float_as_uint(f);
    unsigned r = (x + 0x7FFF + ((x >> 16) & 1)) >> 16;   // RNE
    return (unsigned short)r;
}

// ---------------------------------------------------------------- utilities
__global__ void zero_i32(int* __restrict__ p, int n) {
    int i = blockIdx.x * blockDim.x + threadIdx.x;
    if (i < n) p[i] = 0;
}
__global__ void zero_f32(float* __restrict__ p, int n) {
    int i = blockIdx.x * blockDim.x + threadIdx.x;
    if (i < n) p[i] = 0.0f;
}

// fp32 [R][C] -> bf16 [R][CP], zero-padded columns
__global__ void conv_w(const float* __restrict__ w, unsigned short* __restrict__ o,
                       int R, int C, int CP) {
    int t = blockIdx.x * blockDim.x + threadIdx.x;
    if (t >= R * CP) return;
    int r = t / CP, c = t % CP;
    o[t] = (c < C) ? f2bf(w[(size_t)r * C + c]) : (unsigned short)0;
}

// x [n][100] f32 -> xpad [n][128] bf16 (zero pad)
__global__ void conv_x_pad(const float* __restrict__ x, unsigned short* __restrict__ xp, int n) {
    int t = blockIdx.x * blockDim.x + threadIdx.x;
    if (t >= n * 32) return;
    int node = t >> 5, g = t & 31;
    int f0 = g * 4;
    ushort4 o;
    const float* xr = x + (size_t)node * 100;
    o.x = (f0 + 0 < 100) ? f2bf(xr[f0 + 0]) : 0;
    o.y = (f0 + 1 < 100) ? f2bf(xr[f0 + 1]) : 0;
    o.z = (f0 + 2 < 100) ? f2bf(xr[f0 + 2]) : 0;
    o.w = (f0 + 3 < 100) ? f2bf(xr[f0 + 3]) : 0;
    *(ushort4*)(xp + (size_t)node * 128 + f0) = o;
}

// ---------------------------------------------------------------- CSR build
__global__ void count_k(const int* __restrict__ dst, int* __restrict__ counts, int E) {
    int i = blockIdx.x * blockDim.x + threadIdx.x;
    if (i < E) atomicAdd(&counts[dst[i]], 1);
}

__global__ void scan1(const int* __restrict__ counts, int* __restrict__ rp,
                      int* __restrict__ partials, int n) {
    __shared__ int s[256];
    int t = threadIdx.x;
    int i = blockIdx.x * 256 + t;
    int v = (i < n) ? counts[i] : 0;
    s[t] = v;
    __syncthreads();
    for (int off = 1; off < 256; off <<= 1) {
        int u = (t >= off) ? s[t - off] : 0;
        __syncthreads();
        s[t] += u;
        __syncthreads();
    }
    if (i < n) rp[i] = s[t] - v;
    if (t == 255) partials[blockIdx.x] = s[255];
}

__global__ void scan2(int* __restrict__ partials, int nb) {
    __shared__ int s[512];
    int t = threadIdx.x;
    int v = (t < nb) ? partials[t] : 0;
    s[t] = v;
    __syncthreads();
    for (int off = 1; off < 512; off <<= 1) {
        int u = (t >= off) ? s[t - off] : 0;
        __syncthreads();
        s[t] += u;
        __syncthreads();
    }
    if (t < nb) partials[t] = s[t] - v;
}

__global__ void scan3(int* __restrict__ rp, const int* __restrict__ partials, int n, int E) {
    int i = blockIdx.x * blockDim.x + threadIdx.x;
    if (i < n) rp[i] += partials[i >> 8];
    if (i == 0) rp[n] = E;
}

__global__ void fill_k(const int* __restrict__ src, const int* __restrict__ dst,
                       const int* __restrict__ rp, int* __restrict__ cursor,
                       int* __restrict__ col, int E) {
    int i = blockIdx.x * blockDim.x + threadIdx.x;
    if (i < E) {
        int d = dst[i];
        int pos = atomicAdd(&cursor[d], 1);
        col[rp[d] + pos] = src[i];
    }
}

// ------------------------------------------------------- gather aggregation
// D=256: one 64-lane wave per node, lane covers 4 bf16 (8B)
__global__ __launch_bounds__(256) void agg_bf16_256(
    const unsigned short* __restrict__ x, const int* __restrict__ rp,
    const int* __restrict__ col, unsigned short* __restrict__ out, int n) {
    int wave = threadIdx.x >> 6, lane = threadIdx.x & 63;
    int node = blockIdx.x * 4 + wave;
    if (node >= n) return;
    int s = rp[node], e = rp[node + 1];
    float a0 = 0, a1 = 0, a2 = 0, a3 = 0;
    for (int i = s; i < e; ++i) {
        int r = col[i];
        ushort4 v = *(const ushort4*)(x + (size_t)r * 256 + lane * 4);
        a0 += bf2f(v.x); a1 += bf2f(v.y); a2 += bf2f(v.z); a3 += bf2f(v.w);
    }
    float sc = 1.0f / fmaxf((float)(e - s), 1.0f);
    ushort4 o;
    o.x = f2bf(a0 * sc); o.y = f2bf(a1 * sc); o.z = f2bf(a2 * sc); o.w = f2bf(a3 * sc);
    *(ushort4*)(out + (size_t)node * 256 + lane * 4) = o;
}

// D=128: 32-lane team, 2 nodes per wave
__global__ __launch_bounds__(256) void agg_bf16_128(
    const unsigned short* __restrict__ x, const int* __restrict__ rp,
    const int* __restrict__ col, unsigned short* __restrict__ out, int n) {
    int wave = threadIdx.x >> 6, lane = threadIdx.x & 63;
    int node = blockIdx.x * 8 + wave * 2 + (lane >> 5);
    int l32 = lane & 31;
    if (node >= n) return;
    int s = rp[node], e = rp[node + 1];
    float a0 = 0, a1 = 0, a2 = 0, a3 = 0;
    for (int i = s; i < e; ++i) {
        int r = col[i];
        ushort4 v = *(const ushort4*)(x + (size_t)r * 128 + l32 * 4);
        a0 += bf2f(v.x); a1 += bf2f(v.y); a2 += bf2f(v.z); a3 += bf2f(v.w);
    }
    float sc = 1.0f / fmaxf((float)(e - s), 1.0f);
    ushort4 o;
    o.x = f2bf(a0 * sc); o.y = f2bf(a1 * sc); o.z = f2bf(a2 * sc); o.w = f2bf(a3 * sc);
    *(ushort4*)(out + (size_t)node * 128 + l32 * 4) = o;
}

// ------------------------------------------------- fused SAGE linear (MFMA)
// out[node][f] = bias[f] + x·Wr^T (+ agg·Wl^T); bf16 in, f32 acc.
// Block: 256 threads = 4 waves; wave w -> nodes [blk*64+16w, +16); full DOUT cols.
// W staged per k-step into LDS in MFMA fragment order (lane-linear b128 reads).
template <int KTOT, int DOUT, bool HAS_AGG, bool RELU, bool STF32, bool STBF16>
__global__ __launch_bounds__(256) void sage_mfma(
    const unsigned short* __restrict__ xp, const unsigned short* __restrict__ ap,
    const unsigned short* __restrict__ Wr, const unsigned short* __restrict__ Wl,
    const float* __restrict__ bias,
    float* __restrict__ outf, unsigned short* __restrict__ outb, int n) {
    constexpr int CT = DOUT / 16;        // col tiles
    constexpr int NSRC = HAS_AGG ? 2 : 1;
    constexpr int FR = DOUT * 4;         // 16B frags per source per kstep
    __shared__ __align__(16) unsigned short lds[NSRC * FR * 8];

    const int t = threadIdx.x;
    const int wave = t >> 6, lane = t & 63;
    const int node0 = blockIdx.x * 64 + wave * 16;
    const bool active = node0 < n;       // n % 16 == 0 -> tile all-valid or all-invalid
    const int lcol = lane & 15, lq = lane >> 4;

    f32x4 acc[CT];
#pragma unroll
    for (int c = 0; c < CT; ++c) {
        float b = bias[c * 16 + lcol];
        acc[c][0] = b; acc[c][1] = b; acc[c][2] = b; acc[c][3] = b;
    }

    const unsigned short* aRow  = xp + (size_t)(node0 + lcol) * KTOT + lq * 8;
    const unsigned short* aRow2 = HAS_AGG ? (ap + (size_t)(node0 + lcol) * KTOT + lq * 8) : xp;

    for (int ks = 0; ks < KTOT / 32; ++ks) {
        // stage W fragments: frag(ct,l) = W[ct*16+(l&15)][ks*32+(l>>4)*8 .. +7]
        for (int r = t; r < NSRC * FR; r += 256) {
            int srcSel = r / FR;
            int id = r % FR;
            int ct = id >> 6, l = id & 63;
            const unsigned short* W = (srcSel == 0) ? Wr : Wl;
            uint4 v = *(const uint4*)(W + (size_t)(ct * 16 + (l & 15)) * KTOT + ks * 32 + (l >> 4) * 8);
            *(uint4*)(lds + (size_t)r * 8) = v;
        }
        __syncthreads();
        if (active) {
            short8 a = *(const short8*)(aRow + ks * 32);
            short8 a2;
            if (HAS_AGG) a2 = *(const short8*)(aRow2 + ks * 32);
            const short8* bf = (const short8*)lds;
#pragma unroll
            for (int c = 0; c < CT; ++c)
                acc[c] = __builtin_amdgcn_mfma_f32_16x16x32_bf16(a, bf[c * 64 + lane], acc[c], 0, 0, 0);
            if (HAS_AGG) {
                const short8* bf2 = bf + FR;
#pragma unroll
                for (int c = 0; c < CT; ++c)
                    acc[c] = __builtin_amdgcn_mfma_f32_16x16x32_bf16(a2, bf2[c * 64 + lane], acc[c], 0, 0, 0);
            }
        }
        __syncthreads();
    }
    if (!active) return;

#pragma unroll
    for (int c = 0; c < CT; ++c) {
        f32x4 v = acc[c];
        if (RELU) {
            v[0] = fmaxf(v[0], 0.0f); v[1] = fmaxf(v[1], 0.0f);
            v[2] = fmaxf(v[2], 0.0f); v[3] = fmaxf(v[3], 0.0f);
        }
#pragma unroll
        for (int j = 0; j < 4; ++j) {
            size_t row = (size_t)node0 + lq * 4 + j;
            int colI = c * 16 + lcol;
            if (STF32) outf[row * DOUT + colI] = v[j];
            if (STBF16) outb[row * DOUT + colI] = f2bf(v[j]);
        }
    }
}

// ---------------------------------------------------------------- BatchNorm
__global__ void bn_partial(const float* __restrict__ z, float* __restrict__ sums, int n) {
    int f = threadIdx.x & 127;
    int half = threadIdx.x >> 7;
    float s = 0.0f, s2 = 0.0f;
    for (int row = blockIdx.x * 2 + half; row < n; row += gridDim.x * 2) {
        float v = z[(size_t)row * 128 + f];
        s += v; s2 += v * v;
    }
    __shared__ float ls[256], ls2[256];
    ls[threadIdx.x] = s; ls2[threadIdx.x] = s2;
    __syncthreads();
    if (half == 0) {
        atomicAdd(&sums[f], s + ls[128 + f]);
        atomicAdd(&sums[128 + f], s2 + ls2[128 + f]);
    }
}

__global__ void bn_finalize(const float* __restrict__ sums, const float* __restrict__ gamma,
                            const float* __restrict__ beta, float* __restrict__ params, int n) {
    int f = threadIdx.x;  // 128 threads
    float mu = sums[f] / (float)n;
    float var = sums[128 + f] / (float)n - mu * mu;
    float inv = rsqrtf(var + EPS_BN);
    float sc = gamma[f] * inv;
    params[f] = sc;
    params[128 + f] = beta[f] - mu * sc;
}

__global__ void bn_apply(float* __restrict__ z, const float* __restrict__ params, int total4) {
    int i = blockIdx.x * blockDim.x + threadIdx.x;
    for (; i < total4; i += gridDim.x * blockDim.x) {
        float4 v = ((float4*)z)[i];
        int f0 = (i & 31) * 4;
        v.x = v.x * params[f0 + 0] + params[128 + f0 + 0];
        v.y = v.y * params[f0 + 1] + params[128 + f0 + 1];
        v.z = v.z * params[f0 + 2] + params[128 + f0 + 2];
        v.w = v.w * params[f0 + 3] + params[128 + f0 + 3];
        ((float4*)z)[i] = v;
    }
}

// ---------------------------------------------------------------- launcher
extern "C" void kernel_launch(void* const* d_in, const int* in_sizes, int n_in,
                              void* d_out, int out_size, void* d_ws, size_t ws_size,
                              hipStream_t stream) {
    const float* x_in  = (const float*)d_in[0];
    const int*   ei    = (const int*)d_in[1];
    const float* Wl0   = (const float*)d_in[2];
    const float* bl0   = (const float*)d_in[3];
    const float* Wr0   = (const float*)d_in[4];
    const float* Wl1   = (const float*)d_in[5];
    const float* bl1   = (const float*)d_in[6];
    const float* Wr1   = (const float*)d_in[7];
    const float* Wl2   = (const float*)d_in[8];
    const float* bl2   = (const float*)d_in[9];
    const float* Wr2   = (const float*)d_in[10];
    const float* Wp    = (const float*)d_in[11];
    const float* bp    = (const float*)d_in[12];
    const float* gamma = (const float*)d_in[13];
    const float* beta  = (const float*)d_in[14];

    const int IN = 100, INP = 128, H = 256, OUT = 256, P = 128;
    const int n = in_sizes[0] / IN;          // 100000
    const int E = in_sizes[1] / 2;           // 1600000
    const int* src = ei;
    const int* dst = ei + E;

    size_t off = 0;
    auto alloc = [&](size_t bytes) -> char* {
        char* p = (char*)d_ws + off;
        off += (bytes + 255) & ~(size_t)255;
        return p;
    };
    int*   counts   = (int*)alloc((size_t)n * 4);
    int*   cursor   = (int*)alloc((size_t)n * 4);
    int*   rp       = (int*)alloc((size_t)(n + 1) * 4);
    int*   partials = (int*)alloc(512 * 4);
    int*   col      = (int*)alloc((size_t)E * 4);
    unsigned short* Wl0b = (unsigned short*)alloc((size_t)H * INP * 2);
    unsigned short* Wr0b = (unsigned short*)alloc((size_t)H * INP * 2);
    unsigned short* Wl1b = (unsigned short*)alloc((size_t)H * H * 2);
    unsigned short* Wr1b = (unsigned short*)alloc((size_t)H * H * 2);
    unsigned short* Wl2b = (unsigned short*)alloc((size_t)OUT * H * 2);
    unsigned short* Wr2b = (unsigned short*)alloc((size_t)OUT * H * 2);
    unsigned short* Wpb  = (unsigned short*)alloc((size_t)P * OUT * 2);
    float* bnsums   = (float*)alloc(256 * 4);
    float* bnparams = (float*)alloc(256 * 4);
    // activation buffers (bf16), 51.2 MB each
    unsigned short* bufA = (unsigned short*)alloc((size_t)n * H * 2); // xpad+aggpad, later xb2
    unsigned short* bufB = (unsigned short*)alloc((size_t)n * H * 2); // h1, later agg2
    unsigned short* bufC = (unsigned short*)alloc((size_t)n * H * 2); // agg1
    unsigned short* bufD = (unsigned short*)alloc((size_t)n * H * 2); // h2

    unsigned short* xpad   = bufA;                        // [n][128]
    unsigned short* aggpad = bufA + (size_t)n * INP;      // [n][128]
    unsigned short* h1b  = bufB;
    unsigned short* agg1 = bufC;
    unsigned short* h2b  = bufD;
    unsigned short* agg2 = bufB;                          // reuse (h1 dead)
    unsigned short* xb2  = bufA;                          // reuse (xpad/aggpad dead)

    float* out_x = (float*)d_out;                  // [n][256] final x
    float* z     = out_x + (size_t)n * OUT;        // [n][128] projection/BN output

    const int nb = (n + 255) / 256;
    const int gemm_grid = (n + 63) / 64;

    // --- CSR build ---
    zero_i32<<<nb, 256, 0, stream>>>(counts, n);
    zero_i32<<<nb, 256, 0, stream>>>(cursor, n);
    zero_f32<<<1, 256, 0, stream>>>(bnsums, 256);
    count_k<<<(E + 255) / 256, 256, 0, stream>>>(dst, counts, E);
    scan1<<<nb, 256, 0, stream>>>(counts, rp, partials, n);
    scan2<<<1, 512, 0, stream>>>(partials, nb);
    scan3<<<nb, 256, 0, stream>>>(rp, partials, n, E);
    fill_k<<<(E + 255) / 256, 256, 0, stream>>>(src, dst, rp, cursor, col, E);

    // --- dtype conversions ---
    conv_x_pad<<<(n * 32 + 255) / 256, 256, 0, stream>>>(x_in, xpad, n);
    conv_w<<<(H * INP + 255) / 256, 256, 0, stream>>>(Wl0, Wl0b, H, IN, INP);
    conv_w<<<(H * INP + 255) / 256, 256, 0, stream>>>(Wr0, Wr0b, H, IN, INP);
    conv_w<<<(H * H + 255) / 256, 256, 0, stream>>>(Wl1, Wl1b, H, H, H);
    conv_w<<<(H * H + 255) / 256, 256, 0, stream>>>(Wr1, Wr1b, H, H, H);
    conv_w<<<(OUT * H + 255) / 256, 256, 0, stream>>>(Wl2, Wl2b, OUT, H, H);
    conv_w<<<(OUT * H + 255) / 256, 256, 0, stream>>>(Wr2, Wr2b, OUT, H, H);
    conv_w<<<(P * OUT + 255) / 256, 256, 0, stream>>>(Wp, Wpb, P, OUT, OUT);

    // --- layer 0: 128(pad) -> 256, relu ---
    agg_bf16_128<<<n / 8, 256, 0, stream>>>(xpad, rp, col, aggpad, n);
    sage_mfma<128, 256, true, true, false, true><<<gemm_grid, 256, 0, stream>>>(
        xpad, aggpad, Wr0b, Wl0b, bl0, nullptr, h1b, n);

    // --- layer 1: 256 -> 256, relu ---
    agg_bf16_256<<<n / 4, 256, 0, stream>>>(h1b, rp, col, agg1, n);
    sage_mfma<256, 256, true, true, false, true><<<gemm_grid, 256, 0, stream>>>(
        h1b, agg1, Wr1b, Wl1b, bl1, nullptr, h2b, n);

    // --- layer 2: 256 -> 256, no relu; f32 -> d_out, bf16 copy for projection ---
    agg_bf16_256<<<n / 4, 256, 0, stream>>>(h2b, rp, col, agg2, n);
    sage_mfma<256, 256, true, false, true, true><<<gemm_grid, 256, 0, stream>>>(
        h2b, agg2, Wr2b, Wl2b, bl2, out_x, xb2, n);

    // --- projection head: 256 -> 128 ---
    sage_mfma<256, 128, false, false, true, false><<<gemm_grid, 256, 0, stream>>>(
        xb2, nullptr, Wpb, nullptr, bp, z, nullptr, n);

    // --- BatchNorm over z ---
    bn_partial<<<256, 256, 0, stream>>>(z, bnsums, n);
    bn_finalize<<<1, 128, 0, stream>>>(bnsums, gamma, beta, bnparams, n);
    bn_apply<<<2048, 256, 0, stream>>>(z, bnparams, n * (P / 4));
}

// Round 3
// 821.811 us; speedup vs baseline: 2.6028x; 1.1956x over previous
//
#include <hip/hip_runtime.h>
#include <hip/hip_bf16.h>

#define EPS_BN 1e-5f

using short8  = __attribute__((ext_vector_type(8))) short;
using ushort8 = __attribute__((ext_vector_type(8))) unsigned short;
using f32x4   = __attribute__((ext_vector_type(4))) float;

__device__ inline float bf2f(unsigned short u) {
    union { unsigned i; float f; } c; c.i = ((unsigned)u) << 16; return c.f;
}
__device__ inline unsigned short f2bf(float f) {
    unsigned x = __float_as_uint(f);
    unsigned r = (x + 0x7FFF + ((x >> 16) & 1)) >> 16;   // RNE
    return (unsigned short)r;
}

// ---------------------------------------------------------------- utilities
__global__ void zero_i32(int* __restrict__ p, int n) {
    int i = blockIdx.x * blockDim.x + threadIdx.x;
    if (i < n) p[i] = 0;
}
__global__ void zero_f32(float* __restrict__ p, int n) {
    int i = blockIdx.x * blockDim.x + threadIdx.x;
    if (i < n) p[i] = 0.0f;
}

// fp32 [R][C] -> bf16 [R][CP], zero-padded columns
__global__ void conv_w(const float* __restrict__ w, unsigned short* __restrict__ o,
                       int R, int C, int CP) {
    int t = blockIdx.x * blockDim.x + threadIdx.x;
    if (t >= R * CP) return;
    int r = t / CP, c = t % CP;
    o[t] = (c < C) ? f2bf(w[(size_t)r * C + c]) : (unsigned short)0;
}

// x [n][100] f32 -> xpad [n][128] bf16 (zero pad)
__global__ void conv_x_pad(const float* __restrict__ x, unsigned short* __restrict__ xp, int n) {
    int t = blockIdx.x * blockDim.x + threadIdx.x;
    if (t >= n * 32) return;
    int node = t >> 5, g = t & 31;
    int f0 = g * 4;
    ushort4 o;
    const float* xr = x + (size_t)node * 100;
    o.x = (f0 + 0 < 100) ? f2bf(xr[f0 + 0]) : 0;
    o.y = (f0 + 1 < 100) ? f2bf(xr[f0 + 1]) : 0;
    o.z = (f0 + 2 < 100) ? f2bf(xr[f0 + 2]) : 0;
    o.w = (f0 + 3 < 100) ? f2bf(xr[f0 + 3]) : 0;
    *(ushort4*)(xp + (size_t)node * 128 + f0) = o;
}

// ---------------------------------------------------------------- CSR build
__global__ void count_k(const int* __restrict__ dst, int* __restrict__ counts, int E) {
    int i = blockIdx.x * blockDim.x + threadIdx.x;
    if (i < E) atomicAdd(&counts[dst[i]], 1);
}

__global__ void scan1(const int* __restrict__ counts, int* __restrict__ rp,
                      int* __restrict__ partials, int n) {
    __shared__ int s[256];
    int t = threadIdx.x;
    int i = blockIdx.x * 256 + t;
    int v = (i < n) ? counts[i] : 0;
    s[t] = v;
    __syncthreads();
    for (int off = 1; off < 256; off <<= 1) {
        int u = (t >= off) ? s[t - off] : 0;
        __syncthreads();
        s[t] += u;
        __syncthreads();
    }
    if (i < n) rp[i] = s[t] - v;
    if (t == 255) partials[blockIdx.x] = s[255];
}

__global__ void scan2(int* __restrict__ partials, int nb) {
    __shared__ int s[512];
    int t = threadIdx.x;
    int v = (t < nb) ? partials[t] : 0;
    s[t] = v;
    __syncthreads();
    for (int off = 1; off < 512; off <<= 1) {
        int u = (t >= off) ? s[t - off] : 0;
        __syncthreads();
        s[t] += u;
        __syncthreads();
    }
    if (t < nb) partials[t] = s[t] - v;
}

__global__ void scan3(int* __restrict__ rp, const int* __restrict__ partials, int n, int E) {
    int i = blockIdx.x * blockDim.x + threadIdx.x;
    if (i < n) rp[i] += partials[i >> 8];
    if (i == 0) rp[n] = E;
}

__global__ void fill_k(const int* __restrict__ src, const int* __restrict__ dst,
                       const int* __restrict__ rp, int* __restrict__ cursor,
                       int* __restrict__ col, int E) {
    int i = blockIdx.x * blockDim.x + threadIdx.x;
    if (i < E) {
        int d = dst[i];
        int pos = atomicAdd(&cursor[d], 1);
        col[rp[d] + pos] = src[i];
    }
}

// ------------------------------------------------------- gather aggregation
// D=256: one wave per node. Lane covers 16B (8 bf16); halves (32 lanes) take
// alternating neighbors -> one load instruction fetches 2 rows; unroll 4 -> 8
// neighbors / trip, 4 loads in flight per lane.
__global__ __launch_bounds__(256) void agg_bf16_256(
    const unsigned short* __restrict__ x, const int* __restrict__ rp,
    const int* __restrict__ col, unsigned short* __restrict__ out, int n) {
    int wave = threadIdx.x >> 6, lane = threadIdx.x & 63;
    int node = blockIdx.x * 4 + wave;
    if (node >= n) return;
    int s = rp[node], e = rp[node + 1];
    int deg = e - s;
    int h = lane >> 5;       // neighbor parity within pair
    int l32 = lane & 31;     // 8-elem chunk id

    float a[8] = {0, 0, 0, 0, 0, 0, 0, 0};
    int base = 0;
    for (; base + 8 <= deg; base += 8) {
        int i = s + base + h;
        int r0 = col[i], r1 = col[i + 2], r2 = col[i + 4], r3 = col[i + 6];
        ushort8 v0 = *(const ushort8*)(x + (size_t)r0 * 256 + l32 * 8);
        ushort8 v1 = *(const ushort8*)(x + (size_t)r1 * 256 + l32 * 8);
        ushort8 v2 = *(const ushort8*)(x + (size_t)r2 * 256 + l32 * 8);
        ushort8 v3 = *(const ushort8*)(x + (size_t)r3 * 256 + l32 * 8);
#pragma unroll
        for (int j = 0; j < 8; ++j)
            a[j] += bf2f(v0[j]) + bf2f(v1[j]) + bf2f(v2[j]) + bf2f(v3[j]);
    }
    for (int i = s + base + h; i < e; i += 2) {
        int r = col[i];
        ushort8 v = *(const ushort8*)(x + (size_t)r * 256 + l32 * 8);
#pragma unroll
        for (int j = 0; j < 8; ++j) a[j] += bf2f(v[j]);
    }
#pragma unroll
    for (int j = 0; j < 8; ++j) a[j] += __shfl_xor(a[j], 32);

    if (h == 0) {
        float sc = 1.0f / fmaxf((float)deg, 1.0f);
        ushort8 o;
#pragma unroll
        for (int j = 0; j < 8; ++j) o[j] = f2bf(a[j] * sc);
        *(ushort8*)(out + (size_t)node * 256 + l32 * 8) = o;
    }
}

// D=128: one wave per node; quarters (16 lanes) take neighbors i, i+1, i+2, i+3
// -> one load fetches 4 rows; unroll 4 -> 16 neighbors / trip.
__global__ __launch_bounds__(256) void agg_bf16_128(
    const unsigned short* __restrict__ x, const int* __restrict__ rp,
    const int* __restrict__ col, unsigned short* __restrict__ out, int n) {
    int wave = threadIdx.x >> 6, lane = threadIdx.x & 63;
    int node = blockIdx.x * 4 + wave;
    if (node >= n) return;
    int s = rp[node], e = rp[node + 1];
    int deg = e - s;
    int q = lane >> 4;       // neighbor offset within quad
    int l16 = lane & 15;     // 8-elem chunk id

    float a[8] = {0, 0, 0, 0, 0, 0, 0, 0};
    int base = 0;
    for (; base + 16 <= deg; base += 16) {
        int i = s + base + q;
        int r0 = col[i], r1 = col[i + 4], r2 = col[i + 8], r3 = col[i + 12];
        ushort8 v0 = *(const ushort8*)(x + (size_t)r0 * 128 + l16 * 8);
        ushort8 v1 = *(const ushort8*)(x + (size_t)r1 * 128 + l16 * 8);
        ushort8 v2 = *(const ushort8*)(x + (size_t)r2 * 128 + l16 * 8);
        ushort8 v3 = *(const ushort8*)(x + (size_t)r3 * 128 + l16 * 8);
#pragma unroll
        for (int j = 0; j < 8; ++j)
            a[j] += bf2f(v0[j]) + bf2f(v1[j]) + bf2f(v2[j]) + bf2f(v3[j]);
    }
    for (int i = s + base + q; i < e; i += 4) {
        int r = col[i];
        ushort8 v = *(const ushort8*)(x + (size_t)r * 128 + l16 * 8);
#pragma unroll
        for (int j = 0; j < 8; ++j) a[j] += bf2f(v[j]);
    }
#pragma unroll
    for (int j = 0; j < 8; ++j) {
        a[j] += __shfl_xor(a[j], 16);
        a[j] += __shfl_xor(a[j], 32);
    }

    if (lane < 16) {
        float sc = 1.0f / fmaxf((float)deg, 1.0f);
        ushort8 o;
#pragma unroll
        for (int j = 0; j < 8; ++j) o[j] = f2bf(a[j] * sc);
        *(ushort8*)(out + (size_t)node * 128 + l16 * 8) = o;
    }
}

// ------------------------------------------------- fused SAGE linear (MFMA)
// out[node][f] = bias[f] + x·Wr^T (+ agg·Wl^T); bf16 in, f32 acc.
// Block: 256 threads = 4 waves; wave w -> nodes [blk*64+16w, +16); full DOUT cols.
template <int KTOT, int DOUT, bool HAS_AGG, bool RELU, bool STF32, bool STBF16>
__global__ __launch_bounds__(256) void sage_mfma(
    const unsigned short* __restrict__ xp, const unsigned short* __restrict__ ap,
    const unsigned short* __restrict__ Wr, const unsigned short* __restrict__ Wl,
    const float* __restrict__ bias,
    float* __restrict__ outf, unsigned short* __restrict__ outb, int n) {
    constexpr int CT = DOUT / 16;        // col tiles
    constexpr int NSRC = HAS_AGG ? 2 : 1;
    constexpr int FR = DOUT * 4;         // 16B frags per source per kstep
    __shared__ __align__(16) unsigned short lds[NSRC * FR * 8];

    const int t = threadIdx.x;
    const int wave = t >> 6, lane = t & 63;
    const int node0 = blockIdx.x * 64 + wave * 16;
    const bool active = node0 < n;
    const int lcol = lane & 15, lq = lane >> 4;

    f32x4 acc[CT];
#pragma unroll
    for (int c = 0; c < CT; ++c) {
        float b = bias[c * 16 + lcol];
        acc[c][0] = b; acc[c][1] = b; acc[c][2] = b; acc[c][3] = b;
    }

    const unsigned short* aRow  = xp + (size_t)(node0 + lcol) * KTOT + lq * 8;
    const unsigned short* aRow2 = HAS_AGG ? (ap + (size_t)(node0 + lcol) * KTOT + lq * 8) : xp;

    for (int ks = 0; ks < KTOT / 32; ++ks) {
        for (int r = t; r < NSRC * FR; r += 256) {
            int srcSel = r / FR;
            int id = r % FR;
            int ct = id >> 6, l = id & 63;
            const unsigned short* W = (srcSel == 0) ? Wr : Wl;
            uint4 v = *(const uint4*)(W + (size_t)(ct * 16 + (l & 15)) * KTOT + ks * 32 + (l >> 4) * 8);
            *(uint4*)(lds + (size_t)r * 8) = v;
        }
        __syncthreads();
        if (active) {
            short8 a = *(const short8*)(aRow + ks * 32);
            short8 a2;
            if (HAS_AGG) a2 = *(const short8*)(aRow2 + ks * 32);
            const short8* bf = (const short8*)lds;
#pragma unroll
            for (int c = 0; c < CT; ++c)
                acc[c] = __builtin_amdgcn_mfma_f32_16x16x32_bf16(a, bf[c * 64 + lane], acc[c], 0, 0, 0);
            if (HAS_AGG) {
                const short8* bf2 = bf + FR;
#pragma unroll
                for (int c = 0; c < CT; ++c)
                    acc[c] = __builtin_amdgcn_mfma_f32_16x16x32_bf16(a2, bf2[c * 64 + lane], acc[c], 0, 0, 0);
            }
        }
        __syncthreads();
    }
    if (!active) return;

#pragma unroll
    for (int c = 0; c < CT; ++c) {
        f32x4 v = acc[c];
        if (RELU) {
            v[0] = fmaxf(v[0], 0.0f); v[1] = fmaxf(v[1], 0.0f);
            v[2] = fmaxf(v[2], 0.0f); v[3] = fmaxf(v[3], 0.0f);
        }
#pragma unroll
        for (int j = 0; j < 4; ++j) {
            size_t row = (size_t)node0 + lq * 4 + j;
            int colI = c * 16 + lcol;
            if (STF32) outf[row * DOUT + colI] = v[j];
            if (STBF16) outb[row * DOUT + colI] = f2bf(v[j]);
        }
    }
}

// ---------------------------------------------------------------- BatchNorm
__global__ void bn_partial(const float* __restrict__ z, float* __restrict__ sums, int n) {
    int f = threadIdx.x & 127;
    int half = threadIdx.x >> 7;
    float s = 0.0f, s2 = 0.0f;
    for (int row = blockIdx.x * 2 + half; row < n; row += gridDim.x * 2) {
        float v = z[(size_t)row * 128 + f];
        s += v; s2 += v * v;
    }
    __shared__ float ls[256], ls2[256];
    ls[threadIdx.x] = s; ls2[threadIdx.x] = s2;
    __syncthreads();
    if (half == 0) {
        atomicAdd(&sums[f], s + ls[128 + f]);
        atomicAdd(&sums[128 + f], s2 + ls2[128 + f]);
    }
}

__global__ void bn_finalize(const float* __restrict__ sums, const float* __restrict__ gamma,
                            const float* __restrict__ beta, float* __restrict__ params, int n) {
    int f = threadIdx.x;  // 128 threads
    float mu = sums[f] / (float)n;
    float var = sums[128 + f] / (float)n - mu * mu;
    float inv = rsqrtf(var + EPS_BN);
    float sc = gamma[f] * inv;
    params[f] = sc;
    params[128 + f] = beta[f] - mu * sc;
}

__global__ void bn_apply(float* __restrict__ z, const float* __restrict__ params, int total4) {
    int i = blockIdx.x * blockDim.x + threadIdx.x;
    for (; i < total4; i += gridDim.x * blockDim.x) {
        float4 v = ((float4*)z)[i];
        int f0 = (i & 31) * 4;
        v.x = v.x * params[f0 + 0] + params[128 + f0 + 0];
        v.y = v.y * params[f0 + 1] + params[128 + f0 + 1];
        v.z = v.z * params[f0 + 2] + params[128 + f0 + 2];
        v.w = v.w * params[f0 + 3] + params[128 + f0 + 3];
        ((float4*)z)[i] = v;
    }
}

// ---------------------------------------------------------------- launcher
extern "C" void kernel_launch(void* const* d_in, const int* in_sizes, int n_in,
                              void* d_out, int out_size, void* d_ws, size_t ws_size,
                              hipStream_t stream) {
    const float* x_in  = (const float*)d_in[0];
    const int*   ei    = (const int*)d_in[1];
    const float* Wl0   = (const float*)d_in[2];
    const float* bl0   = (const float*)d_in[3];
    const float* Wr0   = (const float*)d_in[4];
    const float* Wl1   = (const float*)d_in[5];
    const float* bl1   = (const float*)d_in[6];
    const float* Wr1   = (const float*)d_in[7];
    const float* Wl2   = (const float*)d_in[8];
    const float* bl2   = (const float*)d_in[9];
    const float* Wr2   = (const float*)d_in[10];
    const float* Wp    = (const float*)d_in[11];
    const float* bp    = (const float*)d_in[12];
    const float* gamma = (const float*)d_in[13];
    const float* beta  = (const float*)d_in[14];

    const int IN = 100, INP = 128, H = 256, OUT = 256, P = 128;
    const int n = in_sizes[0] / IN;          // 100000
    const int E = in_sizes[1] / 2;           // 1600000
    const int* src = ei;
    const int* dst = ei + E;

    size_t off = 0;
    auto alloc = [&](size_t bytes) -> char* {
        char* p = (char*)d_ws + off;
        off += (bytes + 255) & ~(size_t)255;
        return p;
    };
    int*   counts   = (int*)alloc((size_t)n * 4);
    int*   cursor   = (int*)alloc((size_t)n * 4);
    int*   rp       = (int*)alloc((size_t)(n + 1) * 4);
    int*   partials = (int*)alloc(512 * 4);
    int*   col      = (int*)alloc((size_t)E * 4);
    unsigned short* Wl0b = (unsigned short*)alloc((size_t)H * INP * 2);
    unsigned short* Wr0b = (unsigned short*)alloc((size_t)H * INP * 2);
    unsigned short* Wl1b = (unsigned short*)alloc((size_t)H * H * 2);
    unsigned short* Wr1b = (unsigned short*)alloc((size_t)H * H * 2);
    unsigned short* Wl2b = (unsigned short*)alloc((size_t)OUT * H * 2);
    unsigned short* Wr2b = (unsigned short*)alloc((size_t)OUT * H * 2);
    unsigned short* Wpb  = (unsigned short*)alloc((size_t)P * OUT * 2);
    float* bnsums   = (float*)alloc(256 * 4);
    float* bnparams = (float*)alloc(256 * 4);
    unsigned short* bufA = (unsigned short*)alloc((size_t)n * H * 2);
    unsigned short* bufB = (unsigned short*)alloc((size_t)n * H * 2);
    unsigned short* bufC = (unsigned short*)alloc((size_t)n * H * 2);
    unsigned short* bufD = (unsigned short*)alloc((size_t)n * H * 2);

    unsigned short* xpad   = bufA;                        // [n][128]
    unsigned short* aggpad = bufA + (size_t)n * INP;      // [n][128]
    unsigned short* h1b  = bufB;
    unsigned short* agg1 = bufC;
    unsigned short* h2b  = bufD;
    unsigned short* agg2 = bufB;                          // reuse (h1 dead)
    unsigned short* xb2  = bufA;                          // reuse (xpad/aggpad dead)

    float* out_x = (float*)d_out;                  // [n][256] final x
    float* z     = out_x + (size_t)n * OUT;        // [n][128] projection/BN output

    const int nb = (n + 255) / 256;
    const int gemm_grid = (n + 63) / 64;

    // --- CSR build ---
    zero_i32<<<nb, 256, 0, stream>>>(counts, n);
    zero_i32<<<nb, 256, 0, stream>>>(cursor, n);
    zero_f32<<<1, 256, 0, stream>>>(bnsums, 256);
    count_k<<<(E + 255) / 256, 256, 0, stream>>>(dst, counts, E);
    scan1<<<nb, 256, 0, stream>>>(counts, rp, partials, n);
    scan2<<<1, 512, 0, stream>>>(partials, nb);
    scan3<<<nb, 256, 0, stream>>>(rp, partials, n, E);
    fill_k<<<(E + 255) / 256, 256, 0, stream>>>(src, dst, rp, cursor, col, E);

    // --- dtype conversions ---
    conv_x_pad<<<(n * 32 + 255) / 256, 256, 0, stream>>>(x_in, xpad, n);
    conv_w<<<(H * INP + 255) / 256, 256, 0, stream>>>(Wl0, Wl0b, H, IN, INP);
    conv_w<<<(H * INP + 255) / 256, 256, 0, stream>>>(Wr0, Wr0b, H, IN, INP);
    conv_w<<<(H * H + 255) / 256, 256, 0, stream>>>(Wl1, Wl1b, H, H, H);
    conv_w<<<(H * H + 255) / 256, 256, 0, stream>>>(Wr1, Wr1b, H, H, H);
    conv_w<<<(OUT * H + 255) / 256, 256, 0, stream>>>(Wl2, Wl2b, OUT, H, H);
    conv_w<<<(OUT * H + 255) / 256, 256, 0, stream>>>(Wr2, Wr2b, OUT, H, H);
    conv_w<<<(P * OUT + 255) / 256, 256, 0, stream>>>(Wp, Wpb, P, OUT, OUT);

    // --- layer 0: 128(pad) -> 256, relu ---
    agg_bf16_128<<<(n + 3) / 4, 256, 0, stream>>>(xpad, rp, col, aggpad, n);
    sage_mfma<128, 256, true, true, false, true><<<gemm_grid, 256, 0, stream>>>(
        xpad, aggpad, Wr0b, Wl0b, bl0, nullptr, h1b, n);

    // --- layer 1: 256 -> 256, relu ---
    agg_bf16_256<<<(n + 3) / 4, 256, 0, stream>>>(h1b, rp, col, agg1, n);
    sage_mfma<256, 256, true, true, false, true><<<gemm_grid, 256, 0, stream>>>(
        h1b, agg1, Wr1b, Wl1b, bl1, nullptr, h2b, n);

    // --- layer 2: 256 -> 256, no relu; f32 -> d_out, bf16 copy for projection ---
    agg_bf16_256<<<(n + 3) / 4, 256, 0, stream>>>(h2b, rp, col, agg2, n);
    sage_mfma<256, 256, true, false, true, true><<<gemm_grid, 256, 0, stream>>>(
        h2b, agg2, Wr2b, Wl2b, bl2, out_x, xb2, n);

    // --- projection head: 256 -> 128 ---
    sage_mfma<256, 128, false, false, true, false><<<gemm_grid, 256, 0, stream>>>(
        xb2, nullptr, Wpb, nullptr, bp, z, nullptr, n);

    // --- BatchNorm over z ---
    bn_partial<<<256, 256, 0, stream>>>(z, bnsums, n);
    bn_finalize<<<1, 128, 0, stream>>>(bnsums, gamma, beta, bnparams, n);
    bn_apply<<<2048, 256, 0, stream>>>(z, bnparams, n * (P / 4));
}

// Round 4
// 742.403 us; speedup vs baseline: 2.8812x; 1.1070x over previous
//
#include <hip/hip_runtime.h>
#include <hip/hip_bf16.h>

#define EPS_BN 1e-5f

using short8  = __attribute__((ext_vector_type(8))) short;
using ushort8 = __attribute__((ext_vector_type(8))) unsigned short;
using f32x4   = __attribute__((ext_vector_type(4))) float;

typedef const __attribute__((address_space(1))) void* gas_ptr;
typedef __attribute__((address_space(3))) void* las_ptr;

__device__ inline float bf2f(unsigned short u) {
    union { unsigned i; float f; } c; c.i = ((unsigned)u) << 16; return c.f;
}
__device__ inline unsigned short f2bf(float f) {
    unsigned x = __float_as_uint(f);
    unsigned r = (x + 0x7FFF + ((x >> 16) & 1)) >> 16;   // RNE
    return (unsigned short)r;
}

// ---------------------------------------------------------------- utilities
__global__ void zero_i32(int* __restrict__ p, int n) {
    int i = blockIdx.x * blockDim.x + threadIdx.x;
    if (i < n) p[i] = 0;
}
__global__ void zero_f32(float* __restrict__ p, int n) {
    int i = blockIdx.x * blockDim.x + threadIdx.x;
    if (i < n) p[i] = 0.0f;
}

// fp32 [R][C] -> bf16 [R][CP], zero-padded columns
__global__ void conv_w(const float* __restrict__ w, unsigned short* __restrict__ o,
                       int R, int C, int CP) {
    int t = blockIdx.x * blockDim.x + threadIdx.x;
    if (t >= R * CP) return;
    int r = t / CP, c = t % CP;
    o[t] = (c < C) ? f2bf(w[(size_t)r * C + c]) : (unsigned short)0;
}

// x [n][100] f32 -> xpad [n][128] bf16 (zero pad)
__global__ void conv_x_pad(const float* __restrict__ x, unsigned short* __restrict__ xp, int n) {
    int t = blockIdx.x * blockDim.x + threadIdx.x;
    if (t >= n * 32) return;
    int node = t >> 5, g = t & 31;
    int f0 = g * 4;
    ushort4 o;
    const float* xr = x + (size_t)node * 100;
    o.x = (f0 + 0 < 100) ? f2bf(xr[f0 + 0]) : 0;
    o.y = (f0 + 1 < 100) ? f2bf(xr[f0 + 1]) : 0;
    o.z = (f0 + 2 < 100) ? f2bf(xr[f0 + 2]) : 0;
    o.w = (f0 + 3 < 100) ? f2bf(xr[f0 + 3]) : 0;
    *(ushort4*)(xp + (size_t)node * 128 + f0) = o;
}

// ---------------------------------------------------------------- CSR build
__global__ void count_k(const int* __restrict__ dst, int* __restrict__ counts, int E) {
    int i = blockIdx.x * blockDim.x + threadIdx.x;
    if (i < E) atomicAdd(&counts[dst[i]], 1);
}

__global__ void scan1(const int* __restrict__ counts, int* __restrict__ rp,
                      int* __restrict__ partials, int n) {
    __shared__ int s[256];
    int t = threadIdx.x;
    int i = blockIdx.x * 256 + t;
    int v = (i < n) ? counts[i] : 0;
    s[t] = v;
    __syncthreads();
    for (int off = 1; off < 256; off <<= 1) {
        int u = (t >= off) ? s[t - off] : 0;
        __syncthreads();
        s[t] += u;
        __syncthreads();
    }
    if (i < n) rp[i] = s[t] - v;
    if (t == 255) partials[blockIdx.x] = s[255];
}

__global__ void scan2(int* __restrict__ partials, int nb) {
    __shared__ int s[512];
    int t = threadIdx.x;
    int v = (t < nb) ? partials[t] : 0;
    s[t] = v;
    __syncthreads();
    for (int off = 1; off < 512; off <<= 1) {
        int u = (t >= off) ? s[t - off] : 0;
        __syncthreads();
        s[t] += u;
        __syncthreads();
    }
    if (t < nb) partials[t] = s[t] - v;
}

__global__ void scan3(int* __restrict__ rp, const int* __restrict__ partials, int n, int E) {
    int i = blockIdx.x * blockDim.x + threadIdx.x;
    if (i < n) rp[i] += partials[i >> 8];
    if (i == 0) rp[n] = E;
}

__global__ void fill_k(const int* __restrict__ src, const int* __restrict__ dst,
                       const int* __restrict__ rp, int* __restrict__ cursor,
                       int* __restrict__ col, int E) {
    int i = blockIdx.x * blockDim.x + threadIdx.x;
    if (i < E) {
        int d = dst[i];
        int pos = atomicAdd(&cursor[d], 1);
        col[rp[d] + pos] = src[i];
    }
}

// ------------------------------------------------------- gather aggregation
__global__ __launch_bounds__(256) void agg_bf16_256(
    const unsigned short* __restrict__ x, const int* __restrict__ rp,
    const int* __restrict__ col, unsigned short* __restrict__ out, int n) {
    int wave = threadIdx.x >> 6, lane = threadIdx.x & 63;
    int node = blockIdx.x * 4 + wave;
    if (node >= n) return;
    int s = rp[node], e = rp[node + 1];
    int deg = e - s;
    int h = lane >> 5;
    int l32 = lane & 31;

    float a[8] = {0, 0, 0, 0, 0, 0, 0, 0};
    int base = 0;
    for (; base + 8 <= deg; base += 8) {
        int i = s + base + h;
        int r0 = col[i], r1 = col[i + 2], r2 = col[i + 4], r3 = col[i + 6];
        ushort8 v0 = *(const ushort8*)(x + (size_t)r0 * 256 + l32 * 8);
        ushort8 v1 = *(const ushort8*)(x + (size_t)r1 * 256 + l32 * 8);
        ushort8 v2 = *(const ushort8*)(x + (size_t)r2 * 256 + l32 * 8);
        ushort8 v3 = *(const ushort8*)(x + (size_t)r3 * 256 + l32 * 8);
#pragma unroll
        for (int j = 0; j < 8; ++j)
            a[j] += bf2f(v0[j]) + bf2f(v1[j]) + bf2f(v2[j]) + bf2f(v3[j]);
    }
    for (int i = s + base + h; i < e; i += 2) {
        int r = col[i];
        ushort8 v = *(const ushort8*)(x + (size_t)r * 256 + l32 * 8);
#pragma unroll
        for (int j = 0; j < 8; ++j) a[j] += bf2f(v[j]);
    }
#pragma unroll
    for (int j = 0; j < 8; ++j) a[j] += __shfl_xor(a[j], 32);

    if (h == 0) {
        float sc = 1.0f / fmaxf((float)deg, 1.0f);
        ushort8 o;
#pragma unroll
        for (int j = 0; j < 8; ++j) o[j] = f2bf(a[j] * sc);
        *(ushort8*)(out + (size_t)node * 256 + l32 * 8) = o;
    }
}

__global__ __launch_bounds__(256) void agg_bf16_128(
    const unsigned short* __restrict__ x, const int* __restrict__ rp,
    const int* __restrict__ col, unsigned short* __restrict__ out, int n) {
    int wave = threadIdx.x >> 6, lane = threadIdx.x & 63;
    int node = blockIdx.x * 4 + wave;
    if (node >= n) return;
    int s = rp[node], e = rp[node + 1];
    int deg = e - s;
    int q = lane >> 4;
    int l16 = lane & 15;

    float a[8] = {0, 0, 0, 0, 0, 0, 0, 0};
    int base = 0;
    for (; base + 16 <= deg; base += 16) {
        int i = s + base + q;
        int r0 = col[i], r1 = col[i + 4], r2 = col[i + 8], r3 = col[i + 12];
        ushort8 v0 = *(const ushort8*)(x + (size_t)r0 * 128 + l16 * 8);
        ushort8 v1 = *(const ushort8*)(x + (size_t)r1 * 128 + l16 * 8);
        ushort8 v2 = *(const ushort8*)(x + (size_t)r2 * 128 + l16 * 8);
        ushort8 v3 = *(const ushort8*)(x + (size_t)r3 * 128 + l16 * 8);
#pragma unroll
        for (int j = 0; j < 8; ++j)
            a[j] += bf2f(v0[j]) + bf2f(v1[j]) + bf2f(v2[j]) + bf2f(v3[j]);
    }
    for (int i = s + base + q; i < e; i += 4) {
        int r = col[i];
        ushort8 v = *(const ushort8*)(x + (size_t)r * 128 + l16 * 8);
#pragma unroll
        for (int j = 0; j < 8; ++j) a[j] += bf2f(v[j]);
    }
#pragma unroll
    for (int j = 0; j < 8; ++j) {
        a[j] += __shfl_xor(a[j], 16);
        a[j] += __shfl_xor(a[j], 32);
    }

    if (lane < 16) {
        float sc = 1.0f / fmaxf((float)deg, 1.0f);
        ushort8 o;
#pragma unroll
        for (int j = 0; j < 8; ++j) o[j] = f2bf(a[j] * sc);
        *(ushort8*)(out + (size_t)node * 128 + l16 * 8) = o;
    }
}

// ------------------------------------------------- fused SAGE linear (MFMA)
// 512 threads = 8 waves; 128 nodes/block (wave w -> 16 nodes), full DOUT cols.
// W fragments staged via global_load_lds (16B, lane-linear), double-buffered,
// ONE barrier per k-step: stage(ks+1) issued before compute(ks) so the
// __syncthreads vmcnt-drain lands after the MFMA cluster.
template <int KTOT, int DOUT, bool HAS_AGG, bool RELU, bool STF32, bool STBF16>
__global__ __launch_bounds__(512) void sage_mfma(
    const unsigned short* __restrict__ xp, const unsigned short* __restrict__ ap,
    const unsigned short* __restrict__ Wr, const unsigned short* __restrict__ Wl,
    const float* __restrict__ bias,
    float* __restrict__ outf, unsigned short* __restrict__ outb, int n) {
    constexpr int CT = DOUT / 16;          // col tiles
    constexpr int NSRC = HAS_AGG ? 2 : 1;
    constexpr int FR = NSRC == 2 ? DOUT * 4 : DOUT * 4;  // frags per src per kstep
    constexpr int CHUNKS = NSRC * CT;      // 1KB chunks per kstep
    constexpr int CPW = CHUNKS / 8;        // chunks per wave (>=1)
    constexpr int KS = KTOT / 32;
    constexpr int BUFSZ = NSRC * FR * 8;   // ushorts per buffer
    __shared__ __align__(16) unsigned short lds[2 * BUFSZ];

    const int t = threadIdx.x;
    const int wave = t >> 6, lane = t & 63;
    const int node0 = blockIdx.x * 128 + wave * 16;
    const bool active = node0 < n;
    const int lcol = lane & 15, lq = lane >> 4;

    auto stage = [&](int ks, int buf) {
        unsigned short* base = lds + buf * BUFSZ;
#pragma unroll
        for (int i = 0; i < CPW; ++i) {
            int chunk = wave * CPW + i;
            int srcSel = chunk / CT, ct = chunk % CT;
            const unsigned short* W = (srcSel == 0) ? Wr : Wl;
            const unsigned short* g = W + (size_t)(ct * 16 + lcol) * KTOT + ks * 32 + lq * 8;
            unsigned short* l = base + chunk * 512;   // 64 frags x 8 ushorts
            __builtin_amdgcn_global_load_lds((gas_ptr)g, (las_ptr)l, 16, 0, 0);
        }
    };

    f32x4 acc[CT];
#pragma unroll
    for (int c = 0; c < CT; ++c) {
        float b = bias[c * 16 + lcol];
        acc[c][0] = b; acc[c][1] = b; acc[c][2] = b; acc[c][3] = b;
    }

    const unsigned short* aRow  = xp + (size_t)(node0 + lcol) * KTOT + lq * 8;
    const unsigned short* aRow2 = HAS_AGG ? (ap + (size_t)(node0 + lcol) * KTOT + lq * 8) : xp;

    stage(0, 0);
    __syncthreads();

    for (int ks = 0; ks < KS; ++ks) {
        if (ks + 1 < KS) stage(ks + 1, (ks + 1) & 1);
        if (active) {
            short8 a = *(const short8*)(aRow + ks * 32);
            const short8* bf = (const short8*)(lds + (ks & 1) * BUFSZ);
#pragma unroll
            for (int c = 0; c < CT; ++c)
                acc[c] = __builtin_amdgcn_mfma_f32_16x16x32_bf16(a, bf[c * 64 + lane], acc[c], 0, 0, 0);
            if (HAS_AGG) {
                short8 a2 = *(const short8*)(aRow2 + ks * 32);
                const short8* bf2 = bf + FR;
#pragma unroll
                for (int c = 0; c < CT; ++c)
                    acc[c] = __builtin_amdgcn_mfma_f32_16x16x32_bf16(a2, bf2[c * 64 + lane], acc[c], 0, 0, 0);
            }
        }
        __syncthreads();
    }
    if (!active) return;

#pragma unroll
    for (int c = 0; c < CT; ++c) {
        f32x4 v = acc[c];
        if (RELU) {
            v[0] = fmaxf(v[0], 0.0f); v[1] = fmaxf(v[1], 0.0f);
            v[2] = fmaxf(v[2], 0.0f); v[3] = fmaxf(v[3], 0.0f);
        }
#pragma unroll
        for (int j = 0; j < 4; ++j) {
            size_t row = (size_t)node0 + lq * 4 + j;
            int colI = c * 16 + lcol;
            if (STF32) outf[row * DOUT + colI] = v[j];
            if (STBF16) outb[row * DOUT + colI] = f2bf(v[j]);
        }
    }
}

// ---------------------------------------------------------------- BatchNorm
__global__ void bn_partial(const float* __restrict__ z, float* __restrict__ sums, int n) {
    int f = threadIdx.x & 127;
    int half = threadIdx.x >> 7;
    float s = 0.0f, s2 = 0.0f;
    for (int row = blockIdx.x * 2 + half; row < n; row += gridDim.x * 2) {
        float v = z[(size_t)row * 128 + f];
        s += v; s2 += v * v;
    }
    __shared__ float ls[256], ls2[256];
    ls[threadIdx.x] = s; ls2[threadIdx.x] = s2;
    __syncthreads();
    if (half == 0) {
        atomicAdd(&sums[f], s + ls[128 + f]);
        atomicAdd(&sums[128 + f], s2 + ls2[128 + f]);
    }
}

__global__ void bn_finalize(const float* __restrict__ sums, const float* __restrict__ gamma,
                            const float* __restrict__ beta, float* __restrict__ params, int n) {
    int f = threadIdx.x;  // 128 threads
    float mu = sums[f] / (float)n;
    float var = sums[128 + f] / (float)n - mu * mu;
    float inv = rsqrtf(var + EPS_BN);
    float sc = gamma[f] * inv;
    params[f] = sc;
    params[128 + f] = beta[f] - mu * sc;
}

__global__ void bn_apply(float* __restrict__ z, const float* __restrict__ params, int total4) {
    int i = blockIdx.x * blockDim.x + threadIdx.x;
    for (; i < total4; i += gridDim.x * blockDim.x) {
        float4 v = ((float4*)z)[i];
        int f0 = (i & 31) * 4;
        v.x = v.x * params[f0 + 0] + params[128 + f0 + 0];
        v.y = v.y * params[f0 + 1] + params[128 + f0 + 1];
        v.z = v.z * params[f0 + 2] + params[128 + f0 + 2];
        v.w = v.w * params[f0 + 3] + params[128 + f0 + 3];
        ((float4*)z)[i] = v;
    }
}

// ---------------------------------------------------------------- launcher
extern "C" void kernel_launch(void* const* d_in, const int* in_sizes, int n_in,
                              void* d_out, int out_size, void* d_ws, size_t ws_size,
                              hipStream_t stream) {
    const float* x_in  = (const float*)d_in[0];
    const int*   ei    = (const int*)d_in[1];
    const float* Wl0   = (const float*)d_in[2];
    const float* bl0   = (const float*)d_in[3];
    const float* Wr0   = (const float*)d_in[4];
    const float* Wl1   = (const float*)d_in[5];
    const float* bl1   = (const float*)d_in[6];
    const float* Wr1   = (const float*)d_in[7];
    const float* Wl2   = (const float*)d_in[8];
    const float* bl2   = (const float*)d_in[9];
    const float* Wr2   = (const float*)d_in[10];
    const float* Wp    = (const float*)d_in[11];
    const float* bp    = (const float*)d_in[12];
    const float* gamma = (const float*)d_in[13];
    const float* beta  = (const float*)d_in[14];

    const int IN = 100, INP = 128, H = 256, OUT = 256, P = 128;
    const int n = in_sizes[0] / IN;          // 100000
    const int E = in_sizes[1] / 2;           // 1600000
    const int* src = ei;
    const int* dst = ei + E;

    size_t off = 0;
    auto alloc = [&](size_t bytes) -> char* {
        char* p = (char*)d_ws + off;
        off += (bytes + 255) & ~(size_t)255;
        return p;
    };
    int*   counts   = (int*)alloc((size_t)n * 4);
    int*   cursor   = (int*)alloc((size_t)n * 4);
    int*   rp       = (int*)alloc((size_t)(n + 1) * 4);
    int*   partials = (int*)alloc(512 * 4);
    int*   col      = (int*)alloc((size_t)E * 4);
    unsigned short* Wl0b = (unsigned short*)alloc((size_t)H * INP * 2);
    unsigned short* Wr0b = (unsigned short*)alloc((size_t)H * INP * 2);
    unsigned short* Wl1b = (unsigned short*)alloc((size_t)H * H * 2);
    unsigned short* Wr1b = (unsigned short*)alloc((size_t)H * H * 2);
    unsigned short* Wl2b = (unsigned short*)alloc((size_t)OUT * H * 2);
    unsigned short* Wr2b = (unsigned short*)alloc((size_t)OUT * H * 2);
    unsigned short* Wpb  = (unsigned short*)alloc((size_t)P * OUT * 2);
    float* bnsums   = (float*)alloc(256 * 4);
    float* bnparams = (float*)alloc(256 * 4);
    unsigned short* bufA = (unsigned short*)alloc((size_t)n * H * 2);
    unsigned short* bufB = (unsigned short*)alloc((size_t)n * H * 2);
    unsigned short* bufC = (unsigned short*)alloc((size_t)n * H * 2);
    unsigned short* bufD = (unsigned short*)alloc((size_t)n * H * 2);

    unsigned short* xpad   = bufA;                        // [n][128]
    unsigned short* aggpad = bufA + (size_t)n * INP;      // [n][128]
    unsigned short* h1b  = bufB;
    unsigned short* agg1 = bufC;
    unsigned short* h2b  = bufD;
    unsigned short* agg2 = bufB;                          // reuse (h1 dead)
    unsigned short* xb2  = bufA;                          // reuse (xpad/aggpad dead)

    float* out_x = (float*)d_out;                  // [n][256] final x
    float* z     = out_x + (size_t)n * OUT;        // [n][128] projection/BN output

    const int nb = (n + 255) / 256;
    const int gemm_grid = (n + 127) / 128;

    // --- CSR build ---
    zero_i32<<<nb, 256, 0, stream>>>(counts, n);
    zero_i32<<<nb, 256, 0, stream>>>(cursor, n);
    zero_f32<<<1, 256, 0, stream>>>(bnsums, 256);
    count_k<<<(E + 255) / 256, 256, 0, stream>>>(dst, counts, E);
    scan1<<<nb, 256, 0, stream>>>(counts, rp, partials, n);
    scan2<<<1, 512, 0, stream>>>(partials, nb);
    scan3<<<nb, 256, 0, stream>>>(rp, partials, n, E);
    fill_k<<<(E + 255) / 256, 256, 0, stream>>>(src, dst, rp, cursor, col, E);

    // --- dtype conversions ---
    conv_x_pad<<<(n * 32 + 255) / 256, 256, 0, stream>>>(x_in, xpad, n);
    conv_w<<<(H * INP + 255) / 256, 256, 0, stream>>>(Wl0, Wl0b, H, IN, INP);
    conv_w<<<(H * INP + 255) / 256, 256, 0, stream>>>(Wr0, Wr0b, H, IN, INP);
    conv_w<<<(H * H + 255) / 256, 256, 0, stream>>>(Wl1, Wl1b, H, H, H);
    conv_w<<<(H * H + 255) / 256, 256, 0, stream>>>(Wr1, Wr1b, H, H, H);
    conv_w<<<(OUT * H + 255) / 256, 256, 0, stream>>>(Wl2, Wl2b, OUT, H, H);
    conv_w<<<(OUT * H + 255) / 256, 256, 0, stream>>>(Wr2, Wr2b, OUT, H, H);
    conv_w<<<(P * OUT + 255) / 256, 256, 0, stream>>>(Wp, Wpb, P, OUT, OUT);

    // --- layer 0: 128(pad) -> 256, relu ---
    agg_bf16_128<<<(n + 3) / 4, 256, 0, stream>>>(xpad, rp, col, aggpad, n);
    sage_mfma<128, 256, true, true, false, true><<<gemm_grid, 512, 0, stream>>>(
        xpad, aggpad, Wr0b, Wl0b, bl0, nullptr, h1b, n);

    // --- layer 1: 256 -> 256, relu ---
    agg_bf16_256<<<(n + 3) / 4, 256, 0, stream>>>(h1b, rp, col, agg1, n);
    sage_mfma<256, 256, true, true, false, true><<<gemm_grid, 512, 0, stream>>>(
        h1b, agg1, Wr1b, Wl1b, bl1, nullptr, h2b, n);

    // --- layer 2: 256 -> 256, no relu; f32 -> d_out, bf16 copy for projection ---
    agg_bf16_256<<<(n + 3) / 4, 256, 0, stream>>>(h2b, rp, col, agg2, n);
    sage_mfma<256, 256, true, false, true, true><<<gemm_grid, 512, 0, stream>>>(
        h2b, agg2, Wr2b, Wl2b, bl2, out_x, xb2, n);

    // --- projection head: 256 -> 128 ---
    sage_mfma<256, 128, false, false, true, false><<<gemm_grid, 512, 0, stream>>>(
        xb2, nullptr, Wpb, nullptr, bp, z, nullptr, n);

    // --- BatchNorm over z ---
    bn_partial<<<256, 256, 0, stream>>>(z, bnsums, n);
    bn_finalize<<<1, 128, 0, stream>>>(bnsums, gamma, beta, bnparams, n);
    bn_apply<<<2048, 256, 0, stream>>>(z, bnparams, n * (P / 4));
}